// Round 2
// baseline (10958.797 us; speedup 1.0000x reference)
//
#include <hip/hip_runtime.h>
#include <math.h>

// SuperPoint forward, fp32 direct implementation with adaptive workspace.
// conv2 output lives in d_out's descriptor region (dead before desc is written).
// conv1/2 chain and conv3 chain are row-striped if ws_size is small.

// ---------------------------------------------------------------------------
// Fused conv1a(1->64,3x3)+relu -> conv1b(64->64,3x3)+relu -> maxpool2
// image [8,1,480,640] -> pooled rows [outRow0, pooledRowEnd) of [8,64,240,320]
// ---------------------------------------------------------------------------
__global__ __launch_bounds__(256, 2) void fconv1_kernel(
    const float* __restrict__ img, const float* __restrict__ w1a, const float* __restrict__ b1a,
    const float* __restrict__ w1b, const float* __restrict__ b1b, float* __restrict__ out,
    int y0_base, int pooledRowEnd, int outRow0, int outNRows)
{
    const int H = 480, W = 640, WP = 320;
    const int TILES_X = 20;
    int tx = blockIdx.x % TILES_X, ty = blockIdx.x / TILES_X;
    int x0 = tx * 32, y0 = y0_base + ty * 32;
    int co0 = blockIdx.y * 16;
    int b = blockIdx.z;
    int t = threadIdx.x;

    __shared__ __align__(16) float img_s[36][37];
    __shared__ __align__(16) float a_s[8][34][36];
    __shared__ __align__(16) float w_s[16][8][12];

    for (int idx = t; idx < 36 * 36; idx += 256) {
        int yy = idx / 36, xx = idx % 36;
        int gy = y0 - 2 + yy, gx = x0 - 2 + xx;
        float v = 0.f;
        if (gy >= 0 && gy < H && gx >= 0 && gx < W) v = img[(b * H + gy) * W + gx];
        img_s[yy][xx] = v;
    }

    float acc[16][4];
    #pragma unroll
    for (int ko = 0; ko < 16; ++ko) {
        float bv = b1b[co0 + ko];
        acc[ko][0] = bv; acc[ko][1] = bv; acc[ko][2] = bv; acc[ko][3] = bv;
    }
    int lx = t & 15, ly = t >> 4;

    for (int c0 = 0; c0 < 64; c0 += 8) {
        __syncthreads();
        for (int idx = t; idx < 16 * 8 * 9; idx += 256) {
            int ko = idx / 72, r = idx % 72, c = r / 9, k = r % 9;
            w_s[ko][c][k] = w1b[((co0 + ko) * 64 + c0 + c) * 9 + k];
        }
        for (int idx = t; idx < 8 * 34 * 34; idx += 256) {
            int c = idx / 1156, r = idx % 1156, yy = r / 34, xx = r % 34;
            int ay = y0 + yy - 1, ax = x0 + xx - 1;
            float v = 0.f;
            if (ay >= 0 && ay < H && ax >= 0 && ax < W) {
                float s = b1a[c0 + c];
                const float* wc = &w1a[(c0 + c) * 9];
                #pragma unroll
                for (int ky = 0; ky < 3; ++ky)
                    #pragma unroll
                    for (int kx = 0; kx < 3; ++kx)
                        s = fmaf(img_s[yy + ky][xx + kx], wc[ky * 3 + kx], s);
                v = fmaxf(s, 0.f);
            }
            a_s[c][yy][xx] = v;
        }
        __syncthreads();
        for (int c = 0; c < 8; ++c) {
            float iv[4][4];
            #pragma unroll
            for (int dy = 0; dy < 4; ++dy) {
                float2 p0 = *reinterpret_cast<const float2*>(&a_s[c][2 * ly + dy][2 * lx]);
                float2 p1 = *reinterpret_cast<const float2*>(&a_s[c][2 * ly + dy][2 * lx + 2]);
                iv[dy][0] = p0.x; iv[dy][1] = p0.y; iv[dy][2] = p1.x; iv[dy][3] = p1.y;
            }
            #pragma unroll
            for (int ko = 0; ko < 16; ++ko) {
                const float4* wr = reinterpret_cast<const float4*>(&w_s[ko][c][0]);
                float4 wA = wr[0], wB = wr[1], wC = wr[2];
                #pragma unroll
                for (int q = 0; q < 4; ++q) {
                    const int py = q >> 1, px = q & 1;
                    float a = acc[ko][q];
                    a = fmaf(iv[py][px],         wA.x, a);
                    a = fmaf(iv[py][px + 1],     wA.y, a);
                    a = fmaf(iv[py][px + 2],     wA.z, a);
                    a = fmaf(iv[py + 1][px],     wA.w, a);
                    a = fmaf(iv[py + 1][px + 1], wB.x, a);
                    a = fmaf(iv[py + 1][px + 2], wB.y, a);
                    a = fmaf(iv[py + 2][px],     wB.z, a);
                    a = fmaf(iv[py + 2][px + 1], wB.w, a);
                    a = fmaf(iv[py + 2][px + 2], wC.x, a);
                    acc[ko][q] = a;
                }
            }
        }
    }
    int py = (y0 >> 1) + ly, px = (x0 >> 1) + lx;
    if (py < pooledRowEnd) {
        #pragma unroll
        for (int ko = 0; ko < 16; ++ko) {
            float v0 = fmaxf(acc[ko][0], 0.f), v1 = fmaxf(acc[ko][1], 0.f);
            float v2 = fmaxf(acc[ko][2], 0.f), v3 = fmaxf(acc[ko][3], 0.f);
            out[((b * 64 + co0 + ko) * outNRows + (py - outRow0)) * WP + px] =
                fmaxf(fmaxf(v0, v1), fmaxf(v2, v3));
        }
    }
}

// ---------------------------------------------------------------------------
// Generic conv3x3 + relu (+optional 2x2 maxpool) (+optional NHWC output),
// with row-window support for striped execution.
// in holds global rows [in_row0, in_row1); out holds rows [out_row0, +out_nrows)
// (pooled units if POOL). y_base = global pre-pool out row of tile ty=0.
// y_end = exclusive end of rows to store (pooled units if POOL).
// ---------------------------------------------------------------------------
template<int CIN, bool POOL, bool NHWC>
__global__ __launch_bounds__(256, 2) void conv3x3_kernel(
    const float* __restrict__ in, const float* __restrict__ wt, const float* __restrict__ bias,
    float* __restrict__ out, int H, int W, int COUT, int TILES_X,
    int in_row0, int in_row1, int y_base, int y_end, int out_row0, int out_nrows)
{
    int tx = blockIdx.x % TILES_X, ty = blockIdx.x / TILES_X;
    int x0 = tx * 32, y0 = y_base + ty * 32;
    int co0 = blockIdx.y * 16;
    int b = blockIdx.z;
    int t = threadIdx.x;
    int in_nrows = in_row1 - in_row0;

    __shared__ __align__(16) float in_s[8][34][36];
    __shared__ __align__(16) float w_s[16][8][12];

    float acc[16][4];
    #pragma unroll
    for (int ko = 0; ko < 16; ++ko) {
        float bv = bias[co0 + ko];
        acc[ko][0] = bv; acc[ko][1] = bv; acc[ko][2] = bv; acc[ko][3] = bv;
    }
    int lx = t & 15, ly = t >> 4;

    for (int c0 = 0; c0 < CIN; c0 += 8) {
        __syncthreads();
        for (int idx = t; idx < 8 * 34 * 34; idx += 256) {
            int c = idx / 1156, r = idx % 1156, yy = r / 34, xx = r % 34;
            int gy = y0 + yy - 1, gx = x0 + xx - 1;
            float v = 0.f;
            if (gy >= 0 && gy < H && gx >= 0 && gx < W && gy >= in_row0 && gy < in_row1)
                v = in[((b * CIN + c0 + c) * in_nrows + (gy - in_row0)) * W + gx];
            in_s[c][yy][xx] = v;
        }
        for (int idx = t; idx < 16 * 8 * 9; idx += 256) {
            int ko = idx / 72, r = idx % 72, c = r / 9, k = r % 9;
            w_s[ko][c][k] = wt[((co0 + ko) * CIN + c0 + c) * 9 + k];
        }
        __syncthreads();
        for (int c = 0; c < 8; ++c) {
            float iv[4][4];
            #pragma unroll
            for (int dy = 0; dy < 4; ++dy) {
                float2 p0 = *reinterpret_cast<const float2*>(&in_s[c][2 * ly + dy][2 * lx]);
                float2 p1 = *reinterpret_cast<const float2*>(&in_s[c][2 * ly + dy][2 * lx + 2]);
                iv[dy][0] = p0.x; iv[dy][1] = p0.y; iv[dy][2] = p1.x; iv[dy][3] = p1.y;
            }
            #pragma unroll
            for (int ko = 0; ko < 16; ++ko) {
                const float4* wr = reinterpret_cast<const float4*>(&w_s[ko][c][0]);
                float4 wA = wr[0], wB = wr[1], wC = wr[2];
                #pragma unroll
                for (int q = 0; q < 4; ++q) {
                    const int py = q >> 1, px = q & 1;
                    float a = acc[ko][q];
                    a = fmaf(iv[py][px],         wA.x, a);
                    a = fmaf(iv[py][px + 1],     wA.y, a);
                    a = fmaf(iv[py][px + 2],     wA.z, a);
                    a = fmaf(iv[py + 1][px],     wA.w, a);
                    a = fmaf(iv[py + 1][px + 1], wB.x, a);
                    a = fmaf(iv[py + 1][px + 2], wB.y, a);
                    a = fmaf(iv[py + 2][px],     wB.z, a);
                    a = fmaf(iv[py + 2][px + 1], wB.w, a);
                    a = fmaf(iv[py + 2][px + 2], wC.x, a);
                    acc[ko][q] = a;
                }
            }
        }
    }
    if (POOL) {
        int WP = W >> 1;
        int py = (y0 >> 1) + ly, px = (x0 >> 1) + lx;
        if (py < y_end) {
            #pragma unroll
            for (int ko = 0; ko < 16; ++ko) {
                float v0 = fmaxf(acc[ko][0], 0.f), v1 = fmaxf(acc[ko][1], 0.f);
                float v2 = fmaxf(acc[ko][2], 0.f), v3 = fmaxf(acc[ko][3], 0.f);
                out[((b * COUT + co0 + ko) * out_nrows + (py - out_row0)) * WP + px] =
                    fmaxf(fmaxf(v0, v1), fmaxf(v2, v3));
            }
        }
    } else {
        #pragma unroll
        for (int q = 0; q < 4; ++q) {
            int oy = y0 + 2 * ly + (q >> 1), ox = x0 + 2 * lx + (q & 1);
            if (oy < y_end && oy < H && ox < W) {
                #pragma unroll
                for (int ko = 0; ko < 16; ++ko) {
                    float v = fmaxf(acc[ko][q], 0.f);
                    if (NHWC)
                        out[((b * H + oy) * W + ox) * COUT + co0 + ko] = v;
                    else
                        out[((b * COUT + co0 + ko) * out_nrows + (oy - out_row0)) * W + ox] = v;
                }
            }
        }
    }
}

// ---------------------------------------------------------------------------
// Detector head: 1x1 conv (256->65) + softmax(65) + drop dustbin + pixel
// shuffle to [8,480,640]. cpa is NHWC [38400][256]. One wave per pixel.
// ---------------------------------------------------------------------------
__global__ __launch_bounds__(256) void scores_kernel(
    const float* __restrict__ cpa, const float* __restrict__ wpb,
    const float* __restrict__ bpb, float* __restrict__ sc)
{
    __shared__ __align__(16) float wT[128][66];
    __shared__ __align__(16) float xs[4][256];
    int t = threadIdx.x;
    int wave = t >> 6, lane = t & 63;
    int p = blockIdx.x * 4 + wave;

    float4 xv = reinterpret_cast<const float4*>(&cpa[(size_t)p * 256])[lane];
    xs[wave][lane * 4 + 0] = xv.x; xs[wave][lane * 4 + 1] = xv.y;
    xs[wave][lane * 4 + 2] = xv.z; xs[wave][lane * 4 + 3] = xv.w;

    float a = bpb[lane];
    float a2 = bpb[64];
    for (int k0 = 0; k0 < 256; k0 += 128) {
        __syncthreads();
        for (int idx = t; idx < 65 * 128; idx += 256) {
            int o = idx / 128, i = idx % 128;
            wT[i][o] = wpb[o * 256 + k0 + i];
        }
        __syncthreads();
        for (int i = 0; i < 128; ++i) {
            float xb = xs[wave][k0 + i];
            a  = fmaf(xb, wT[i][lane], a);
            a2 = fmaf(xb, wT[i][64], a2);
        }
    }
    float m = a;
    #pragma unroll
    for (int off = 32; off; off >>= 1) m = fmaxf(m, __shfl_xor(m, off));
    m = fmaxf(m, a2);
    float e = expf(a - m);
    float s = e;
    #pragma unroll
    for (int off = 32; off; off >>= 1) s += __shfl_xor(s, off);
    s += expf(a2 - m);
    float r = e / s;
    int b = p / 4800, hw = p % 4800, h = hw / 80, w = hw % 80;
    int rr = lane >> 3, cc = lane & 7;
    sc[b * 307200 + (h * 8 + rr) * 640 + (w * 8 + cc)] = r;
}

// ---------------------------------------------------------------------------
// NMS: 16x16 tile + radius-3 halo, 7x7 max with -inf padding.
// ---------------------------------------------------------------------------
#define NMS_STAGE(SRC)                                                        \
    __shared__ float ts[22][23];                                              \
    const int H = 480, W = 640;                                               \
    int bx = blockIdx.x * 16, by = blockIdx.y * 16, b = blockIdx.z;           \
    int t = threadIdx.x;                                                      \
    for (int idx = t; idx < 22 * 22; idx += 256) {                            \
        int yy = idx / 22, xx = idx % 22;                                     \
        int gy = by + yy - 3, gx = bx + xx - 3;                               \
        ts[yy][xx] = (gy >= 0 && gy < H && gx >= 0 && gx < W)                 \
                         ? (SRC)[b * 307200 + gy * W + gx] : -INFINITY;       \
    }                                                                         \
    __syncthreads();                                                          \
    int lx = t & 15, ly = t >> 4;                                             \
    float mx = -INFINITY;                                                     \
    _Pragma("unroll")                                                         \
    for (int dy = 0; dy < 7; ++dy)                                            \
        _Pragma("unroll")                                                     \
        for (int dx = 0; dx < 7; ++dx)                                        \
            mx = fmaxf(mx, ts[ly + dy][lx + dx]);                            \
    int p = b * 307200 + (by + ly) * W + (bx + lx);

__global__ __launch_bounds__(256) void nms_max_mask(
    const float* __restrict__ s, float* __restrict__ M)
{
    NMS_STAGE(s)
    M[p] = (ts[ly + 3][lx + 3] == mx) ? 1.f : 0.f;
}

__global__ __launch_bounds__(256) void nms_supp(
    const float* __restrict__ M, const float* __restrict__ s,
    float* __restrict__ supp, float* __restrict__ ss)
{
    NMS_STAGE(M)
    float sup = (mx > 0.f) ? 1.f : 0.f;
    supp[p] = sup;
    ss[p] = (sup > 0.f) ? 0.f : s[p];
}

template<bool LAST>
__global__ __launch_bounds__(256) void nms_update(
    const float* __restrict__ ssb, const float* __restrict__ supp,
    const float* __restrict__ s, float* __restrict__ M, float* __restrict__ outp)
{
    NMS_STAGE(ssb)
    bool new_max = (ts[ly + 3][lx + 3] == mx);
    float mo = M[p];
    float sp = supp[p];
    bool mn = (mo > 0.f) || (new_max && sp == 0.f);
    if (LAST)
        outp[p] = mn ? s[p] : 0.f;
    else
        M[p] = mn ? 1.f : 0.f;
}

// ---------------------------------------------------------------------------
// Descriptor head: 1x1 conv (256->256) + bias + per-pixel L2 normalize,
// NHWC input [38400][256] -> NCHW output [8][256][4800].
// ---------------------------------------------------------------------------
__global__ __launch_bounds__(256, 2) void descdb_kernel(
    const float* __restrict__ cda, const float* __restrict__ wdb,
    const float* __restrict__ bdb, float* __restrict__ outp)
{
    __shared__ __align__(16) float Xs[16][65];
    __shared__ __align__(16) float Ws[16][257];
    int t = threadIdx.x;
    int m0 = blockIdx.x * 64;
    int n_id = t & 31, m_id = t >> 5;

    float acc[8][8];
    #pragma unroll
    for (int nn = 0; nn < 8; ++nn) {
        float bv = bdb[n_id + 32 * nn];
        #pragma unroll
        for (int mm = 0; mm < 8; ++mm) acc[mm][nn] = bv;
    }

    for (int k0 = 0; k0 < 256; k0 += 16) {
        __syncthreads();
        for (int idx = t; idx < 64 * 16; idx += 256) {
            int m = idx / 16, k = idx % 16;
            Xs[k][m] = cda[(size_t)(m0 + m) * 256 + k0 + k];
        }
        for (int idx = t; idx < 256 * 16; idx += 256) {
            int o = idx / 16, k = idx % 16;
            Ws[k][o] = wdb[o * 256 + k0 + k];
        }
        __syncthreads();
        #pragma unroll
        for (int k = 0; k < 16; ++k) {
            float xv[8], wv[8];
            #pragma unroll
            for (int mm = 0; mm < 8; ++mm) xv[mm] = Xs[k][m_id * 8 + mm];
            #pragma unroll
            for (int nn = 0; nn < 8; ++nn) wv[nn] = Ws[k][n_id + 32 * nn];
            #pragma unroll
            for (int mm = 0; mm < 8; ++mm)
                #pragma unroll
                for (int nn = 0; nn < 8; ++nn)
                    acc[mm][nn] = fmaf(xv[mm], wv[nn], acc[mm][nn]);
        }
    }
    #pragma unroll
    for (int mm = 0; mm < 8; ++mm) {
        float sq = 0.f;
        #pragma unroll
        for (int nn = 0; nn < 8; ++nn) sq = fmaf(acc[mm][nn], acc[mm][nn], sq);
        #pragma unroll
        for (int off = 16; off; off >>= 1) sq += __shfl_xor(sq, off);
        float inv = 1.f / sqrtf(sq);
        int P = m0 + m_id * 8 + mm;
        int b = P / 4800, hw = P % 4800;
        #pragma unroll
        for (int nn = 0; nn < 8; ++nn) {
            int o = n_id + 32 * nn;
            outp[(b * 256 + o) * 4800 + hw] = acc[mm][nn] * inv;
        }
    }
}

// ---------------------------------------------------------------------------
static inline size_t max3(size_t a, size_t b, size_t c) {
    size_t m = a > b ? a : b; return m > c ? m : c;
}

extern "C" void kernel_launch(void* const* d_in, const int* in_sizes, int n_in,
                              void* d_out, int out_size, void* d_ws, size_t ws_size,
                              hipStream_t stream)
{
    const float* image = (const float*)d_in[0];
    const float* w1a = (const float*)d_in[1];  const float* b1a = (const float*)d_in[2];
    const float* w1b = (const float*)d_in[3];  const float* b1b = (const float*)d_in[4];
    const float* w2a = (const float*)d_in[5];  const float* b2a = (const float*)d_in[6];
    const float* w2b = (const float*)d_in[7];  const float* b2b = (const float*)d_in[8];
    const float* w3a = (const float*)d_in[9];  const float* b3a = (const float*)d_in[10];
    const float* w3b = (const float*)d_in[11]; const float* b3b = (const float*)d_in[12];
    const float* w4a = (const float*)d_in[13]; const float* b4a = (const float*)d_in[14];
    const float* w4b = (const float*)d_in[15]; const float* b4b = (const float*)d_in[16];
    const float* wPa = (const float*)d_in[17]; const float* bPa = (const float*)d_in[18];
    const float* wPb = (const float*)d_in[19]; const float* bPb = (const float*)d_in[20];
    const float* wDa = (const float*)d_in[21]; const float* bDa = (const float*)d_in[22];
    const float* wDb = (const float*)d_in[23]; const float* bDb = (const float*)d_in[24];

    float* out_sc   = (float*)d_out;            // [8,480,640]
    float* out_nms  = out_sc + 2457600;         // [8,480,640]
    float* out_desc = out_sc + 4915200;         // [8,256,60,80] (= 9,830,400 floats)

    float* ws = (float*)d_ws;
    const size_t ROWF = 163840;                 // floats per row: 64ch*320*8b == 128ch*160*8b
    size_t capf = ws_size / 4;

    // --- plan selection (deterministic: depends only on ws_size) ---
    int S, S3;
    if (capf >= 83558400)       { S = 240; S3 = 120; }   // full buffers
    else if (capf >= 25559040)  { S = 60;  S3 = 120; }
    else                        { S = 32;  S3 = 60;  }
    size_t arows = (S == 240) ? 240 : (size_t)(S + 4);
    size_t brows = (S == 240) ? 240 : (size_t)(S + 2);
    size_t srows = (S3 == 120) ? 120 : (size_t)(S3 + 2);
    size_t P = max3((arows + brows) * ROWF, srows * ROWF, (size_t)9830400);

    float* A    = ws;                       // fconv1 stripe out
    float* B    = ws + arows * ROWF;        // conv2a stripe out
    float* S3b  = ws;                       // conv3a stripe out (A/B dead)
    float* E    = ws + P;                   // conv3b out [8,128,60,80]
    float* F    = ws;                       // conv4a out
    float* G    = E;                        // conv4b out (E dead after conv4a)
    float* Hbuf = ws;                       // cPa / cDa NHWC [38400][256] (F dead)
    float* C    = out_desc;                 // conv2b out [8,64,120,160] (desc region, dead early)
    float* Mb   = ws;                       // NMS scratch (Hbuf dead post-scores)
    float* Sup  = ws + 2457600;
    float* Ss   = ws + 4915200;

    // --- stage 1+2: conv1a+1b+pool -> conv2a -> conv2b+pool, striped ---
    for (int r0 = 0; r0 < 240; r0 += S) {
        int r1 = r0 + S;
        int WA0 = r0 - 2 < 0 ? 0 : r0 - 2, WA1 = r1 + 2 > 240 ? 240 : r1 + 2;
        int nA = WA1 - WA0;
        int tyA = (2 * nA + 31) / 32;
        fconv1_kernel<<<dim3(20 * tyA, 4, 8), 256, 0, stream>>>(
            image, w1a, b1a, w1b, b1b, A, 2 * WA0, WA1, WA0, nA);

        int WB0 = r0 - 1 < 0 ? 0 : r0 - 1, WB1 = r1 + 1 > 240 ? 240 : r1 + 1;
        int nB = WB1 - WB0;
        int tyB = (nB + 31) / 32;
        conv3x3_kernel<64, false, false><<<dim3(10 * tyB, 4, 8), 256, 0, stream>>>(
            A, w2a, b2a, B, 240, 320, 64, 10, WA0, WA1, WB0, WB1, WB0, nB);

        int tyC = (S + 31) / 32;
        conv3x3_kernel<64, true, false><<<dim3(10 * tyC, 4, 8), 256, 0, stream>>>(
            B, w2b, b2b, C, 240, 320, 64, 10, WB0, WB1, r0, r1 / 2, 0, 120);
    }

    // --- stage 3: conv3a -> conv3b+pool, striped ---
    for (int q0 = 0; q0 < 120; q0 += S3) {
        int q1 = q0 + S3;
        int W30 = q0 - 1 < 0 ? 0 : q0 - 1, W31 = q1 + 1 > 120 ? 120 : q1 + 1;
        int n3 = W31 - W30;
        int ty3 = (n3 + 31) / 32;
        conv3x3_kernel<64, false, false><<<dim3(5 * ty3, 8, 8), 256, 0, stream>>>(
            C, w3a, b3a, S3b, 120, 160, 128, 5, 0, 120, W30, W31, W30, n3);

        int ty3b = (S3 + 31) / 32;
        conv3x3_kernel<128, true, false><<<dim3(5 * ty3b, 8, 8), 256, 0, stream>>>(
            S3b, w3b, b3b, E, 120, 160, 128, 5, W30, W31, q0, q1 / 2, 0, 60);
    }

    // --- stage 4 ---
    conv3x3_kernel<128, false, false><<<dim3(6, 8, 8), 256, 0, stream>>>(
        E, w4a, b4a, F, 60, 80, 128, 3, 0, 60, 0, 60, 0, 60);
    conv3x3_kernel<128, false, false><<<dim3(6, 8, 8), 256, 0, stream>>>(
        F, w4b, b4b, G, 60, 80, 128, 3, 0, 60, 0, 60, 0, 60);

    // --- detector head ---
    conv3x3_kernel<128, false, true><<<dim3(6, 16, 8), 256, 0, stream>>>(
        G, wPa, bPa, Hbuf, 60, 80, 256, 3, 0, 60, 0, 60, 0, 60);
    scores_kernel<<<9600, 256, 0, stream>>>(Hbuf, wPb, bPb, out_sc);

    // --- NMS (radius 3, 2 rounds) ---
    nms_max_mask<<<dim3(40, 30, 8), 256, 0, stream>>>(out_sc, Mb);
    nms_supp<<<dim3(40, 30, 8), 256, 0, stream>>>(Mb, out_sc, Sup, Ss);
    nms_update<false><<<dim3(40, 30, 8), 256, 0, stream>>>(Ss, Sup, out_sc, Mb, out_nms);
    nms_supp<<<dim3(40, 30, 8), 256, 0, stream>>>(Mb, out_sc, Sup, Ss);
    nms_update<true><<<dim3(40, 30, 8), 256, 0, stream>>>(Ss, Sup, out_sc, Mb, out_nms);

    // --- descriptor head ---
    conv3x3_kernel<128, false, true><<<dim3(6, 16, 8), 256, 0, stream>>>(
        G, wDa, bDa, Hbuf, 60, 80, 256, 3, 0, 60, 0, 60, 0, 60);
    descdb_kernel<<<600, 256, 0, stream>>>(Hbuf, wDb, bDb, out_desc);
}

// Round 5
// 7621.987 us; speedup vs baseline: 1.4378x; 1.4378x over previous
//
#include <hip/hip_runtime.h>
#include <math.h>

typedef __attribute__((ext_vector_type(8))) _Float16 f16x8;
typedef __attribute__((ext_vector_type(4))) float f32x4;

__device__ __forceinline__ void f32_split(float x, ushort& h, ushort& l) {
    _Float16 hh = (_Float16)x;
    float r = x - (float)hh;
    _Float16 ll = (_Float16)r;
    union { _Float16 f; ushort u; } a, b;
    a.f = hh; b.f = ll;
    h = a.u; l = b.u;
}
__device__ __forceinline__ float h2f(ushort u) {
    union { ushort u; _Float16 f; } v; v.u = u; return (float)v.f;
}

// ---------------------------------------------------------------------------
// Weight transform: fp32 OIHW [CO][CI][3][3] -> f16 hi/lo tap-major [9][CO][CI]
// ---------------------------------------------------------------------------
__global__ void wtr_kernel(const float* __restrict__ src, ushort* __restrict__ dhi,
                           ushort* __restrict__ dlo, int CO, int CI)
{
    int n = CO * CI * 9, coci = CO * CI;
    for (int idx = blockIdx.x * 256 + threadIdx.x; idx < n; idx += gridDim.x * 256) {
        int tp = idx / coci, r = idx % coci;
        int co = r / CI, ci = r % CI;
        ushort h, l;
        f32_split(src[((size_t)co * CI + ci) * 9 + tp], h, l);
        dhi[idx] = h; dlo[idx] = l;
    }
}

// ---------------------------------------------------------------------------
// Split-f16 MFMA implicit-GEMM conv3x3 + relu (+pool), band-striped.
// NHWC activations as two f16 planes (hi at ptr, lo at ptr+pl).
// Each product = 3 MFMAs: hi*whi + lo*whi + hi*wlo (fp32 accumulate).
// Block: 64 px (8x8) x 64 out-ch; 4 waves (2Mx2N). CI chunked by 64.
// Bands: input tensor holds global rows [iy0, iy0+inr); output holds
// [oy0, oy0+onr). Tiles start at y_start; stores guarded to < y_lim
// (y_lim/oy0 in pooled units when POOL).
// ---------------------------------------------------------------------------
template<int CI, bool POOL, bool FUSE1A>
__global__ __launch_bounds__(256, 2) void mconv_kernel(
    const ushort* __restrict__ in, size_t ipl,
    const float* __restrict__ image, const float* __restrict__ w1a,
    const float* __restrict__ b1a,
    const ushort* __restrict__ whi, const ushort* __restrict__ wlo, // [9][COT][CI]
    const float* __restrict__ bias,
    ushort* __restrict__ out, size_t opl,
    int H, int W, int COT, int TXC,
    int iy0, int inr, int y_start, int y_lim, int oy0, int onr)
{
    // LDS carve (ushort): AHI[100*68] ALO[100*68] WB[2][2][64*68]
    __shared__ __align__(16) ushort smem[31008];
    ushort* AHI = smem;                 // 6800
    ushort* ALO = smem + 6800;          // 6800
    ushort* WB  = smem + 13600;         // buf b at +b*8704; lo half at +4352

    int t = threadIdx.x;
    int tx = blockIdx.x % TXC, ty = blockIdx.x / TXC;
    int x0 = tx * 8, y0 = y_start + ty * 8;
    int co0 = blockIdx.y * 64;
    int b = blockIdx.z;

    int lane = t & 63, wid = t >> 6;
    int wm = wid >> 1, wn = wid & 1;
    int fr = lane & 15, fg = lane >> 4;
    int p0 = wm * 32 + fr;
    int py0 = p0 >> 3, px0 = p0 & 7;
    int cb0 = wn * 32 + fr;

    f32x4 acc[2][2];
    {
        float bv0 = bias[co0 + wn * 32 + fr];
        float bv1 = bias[co0 + wn * 32 + 16 + fr];
        acc[0][0] = f32x4{bv0, bv0, bv0, bv0};
        acc[0][1] = f32x4{bv1, bv1, bv1, bv1};
        acc[1][0] = acc[0][0];
        acc[1][1] = acc[0][1];
    }

    const int NC = CI / 64;
    for (int cc = 0; cc < NC; ++cc) {
        __syncthreads();
        // ---- stage A chunk (100 px halo x 64 ch, hi+lo) ----
        if constexpr (FUSE1A) {
            float* img_s = (float*)(WB + 8704);   // buf1 region, free pre-loop
            float* w1a_s = img_s + 144;
            float* b1a_s = w1a_s + 576;
            for (int idx = t; idx < 144; idx += 256) {
                int iy = idx / 12, ix = idx % 12;
                int gy = y0 - 2 + iy, gx = x0 - 2 + ix;
                img_s[idx] = (gy >= 0 && gy < H && gx >= 0 && gx < W)
                                 ? image[((size_t)b * H + gy) * W + gx] : 0.f;
            }
            for (int idx = t; idx < 576; idx += 256) w1a_s[idx] = w1a[idx];
            if (t < 64) b1a_s[t] = b1a[t];
            __syncthreads();
            for (int idx = t; idx < 6400; idx += 256) {   // 100 px x 64 ch
                int hp = idx >> 6, c = idx & 63;
                int hy = y0 - 1 + hp / 10, hx = x0 - 1 + hp % 10;
                float v = 0.f;
                if (hy >= 0 && hy < H && hx >= 0 && hx < W) {
                    int iy = hp / 10, ix = hp % 10;
                    float s = b1a_s[c];
                    #pragma unroll
                    for (int ky = 0; ky < 3; ++ky)
                        #pragma unroll
                        for (int kx = 0; kx < 3; ++kx)
                            s = fmaf(img_s[(iy + ky) * 12 + ix + kx],
                                     w1a_s[c * 9 + ky * 3 + kx], s);
                    v = fmaxf(s, 0.f);
                }
                ushort h, l; f32_split(v, h, l);
                AHI[hp * 68 + c] = h;
                ALO[hp * 68 + c] = l;
            }
        } else {
            for (int idx = t; idx < 800; idx += 256) {
                int hp = idx >> 3, c8 = idx & 7;
                int hy = y0 - 1 + hp / 10, hx = x0 - 1 + hp % 10;
                int4 vh = make_int4(0, 0, 0, 0), vl = make_int4(0, 0, 0, 0);
                if (hy >= iy0 && hy < iy0 + inr && hx >= 0 && hx < W) {
                    size_t a = (((size_t)b * inr + (hy - iy0)) * W + hx) * CI + cc * 64 + c8 * 8;
                    vh = *reinterpret_cast<const int4*>(&in[a]);
                    vl = *reinterpret_cast<const int4*>(&in[a + ipl]);
                }
                *reinterpret_cast<int4*>(&AHI[hp * 68 + c8 * 8]) = vh;
                *reinterpret_cast<int4*>(&ALO[hp * 68 + c8 * 8]) = vl;
            }
        }
        // ---- stage W tap 0 of this chunk into buf 0 ----
        for (int idx = t; idx < 512; idx += 256) {
            int co = idx >> 3, c8 = idx & 7;
            size_t a = ((size_t)(co0 + co)) * CI + cc * 64 + c8 * 8;
            *reinterpret_cast<int4*>(&WB[co * 68 + c8 * 8]) =
                *reinterpret_cast<const int4*>(&whi[a]);
            *reinterpret_cast<int4*>(&WB[4352 + co * 68 + c8 * 8]) =
                *reinterpret_cast<const int4*>(&wlo[a]);
        }
        __syncthreads();

        for (int tap = 0; tap < 9; ++tap) {
            int cur = tap & 1;
            if (tap < 8) {   // prefetch next tap into other buffer
                int nb = (1 - cur) * 8704;
                for (int idx = t; idx < 512; idx += 256) {
                    int co = idx >> 3, c8 = idx & 7;
                    size_t a = ((size_t)(tap + 1) * COT + co0 + co) * CI + cc * 64 + c8 * 8;
                    *reinterpret_cast<int4*>(&WB[nb + co * 68 + c8 * 8]) =
                        *reinterpret_cast<const int4*>(&whi[a]);
                    *reinterpret_cast<int4*>(&WB[nb + 4352 + co * 68 + c8 * 8]) =
                        *reinterpret_cast<const int4*>(&wlo[a]);
                }
            }
            int ky = tap / 3, kx = tap % 3;
            int h0 = (py0 + ky) * 10 + px0 + kx;
            const ushort* WH = WB + cur * 8704;
            const ushort* WL = WH + 4352;
            #pragma unroll
            for (int kc = 0; kc < 2; ++kc) {
                int ko = kc * 32 + fg * 8;
                f16x8 ah0 = *reinterpret_cast<const f16x8*>(&AHI[h0 * 68 + ko]);
                f16x8 ah1 = *reinterpret_cast<const f16x8*>(&AHI[(h0 + 20) * 68 + ko]);
                f16x8 al0 = *reinterpret_cast<const f16x8*>(&ALO[h0 * 68 + ko]);
                f16x8 al1 = *reinterpret_cast<const f16x8*>(&ALO[(h0 + 20) * 68 + ko]);
                f16x8 qh0 = *reinterpret_cast<const f16x8*>(&WH[cb0 * 68 + ko]);
                f16x8 qh1 = *reinterpret_cast<const f16x8*>(&WH[(cb0 + 16) * 68 + ko]);
                f16x8 ql0 = *reinterpret_cast<const f16x8*>(&WL[cb0 * 68 + ko]);
                f16x8 ql1 = *reinterpret_cast<const f16x8*>(&WL[(cb0 + 16) * 68 + ko]);
                acc[0][0] = __builtin_amdgcn_mfma_f32_16x16x32_f16(ah0, qh0, acc[0][0], 0, 0, 0);
                acc[0][0] = __builtin_amdgcn_mfma_f32_16x16x32_f16(al0, qh0, acc[0][0], 0, 0, 0);
                acc[0][0] = __builtin_amdgcn_mfma_f32_16x16x32_f16(ah0, ql0, acc[0][0], 0, 0, 0);
                acc[0][1] = __builtin_amdgcn_mfma_f32_16x16x32_f16(ah0, qh1, acc[0][1], 0, 0, 0);
                acc[0][1] = __builtin_amdgcn_mfma_f32_16x16x32_f16(al0, qh1, acc[0][1], 0, 0, 0);
                acc[0][1] = __builtin_amdgcn_mfma_f32_16x16x32_f16(ah0, ql1, acc[0][1], 0, 0, 0);
                acc[1][0] = __builtin_amdgcn_mfma_f32_16x16x32_f16(ah1, qh0, acc[1][0], 0, 0, 0);
                acc[1][0] = __builtin_amdgcn_mfma_f32_16x16x32_f16(al1, qh0, acc[1][0], 0, 0, 0);
                acc[1][0] = __builtin_amdgcn_mfma_f32_16x16x32_f16(ah1, ql0, acc[1][0], 0, 0, 0);
                acc[1][1] = __builtin_amdgcn_mfma_f32_16x16x32_f16(ah1, qh1, acc[1][1], 0, 0, 0);
                acc[1][1] = __builtin_amdgcn_mfma_f32_16x16x32_f16(al1, qh1, acc[1][1], 0, 0, 0);
                acc[1][1] = __builtin_amdgcn_mfma_f32_16x16x32_f16(ah1, ql1, acc[1][1], 0, 0, 0);
            }
            __syncthreads();
        }
    }

    if constexpr (POOL) {
        float* olds = (float*)smem;   // [64 px][68]
        #pragma unroll
        for (int mi = 0; mi < 2; ++mi)
            #pragma unroll
            for (int nj = 0; nj < 2; ++nj)
                #pragma unroll
                for (int r = 0; r < 4; ++r) {
                    int i = wm * 32 + mi * 16 + fg * 4 + r;
                    int c = wn * 32 + nj * 16 + fr;
                    olds[i * 68 + c] = fmaxf(acc[mi][nj][r], 0.f);
                }
        __syncthreads();
        int q = t >> 4, cg = (t & 15) * 4;
        int qy = q >> 2, qx = q & 3;
        int i00 = qy * 16 + qx * 2;
        int Wp = W >> 1;
        int py = (y0 >> 1) + qy, px = (x0 >> 1) + qx;
        if (py < y_lim) {
            ushort4 rh, rl;
            #pragma unroll
            for (int j = 0; j < 4; ++j) {
                float a = olds[i00 * 68 + cg + j],       bq = olds[(i00 + 1) * 68 + cg + j];
                float c = olds[(i00 + 8) * 68 + cg + j], d = olds[(i00 + 9) * 68 + cg + j];
                float m = fmaxf(fmaxf(a, bq), fmaxf(c, d));
                ushort h, l; f32_split(m, h, l);
                ((ushort*)&rh)[j] = h; ((ushort*)&rl)[j] = l;
            }
            size_t oa = (((size_t)b * onr + (py - oy0)) * Wp + px) * COT + co0 + cg;
            *reinterpret_cast<ushort4*>(&out[oa]) = rh;
            *reinterpret_cast<ushort4*>(&out[oa + opl]) = rl;
        }
    } else {
        #pragma unroll
        for (int mi = 0; mi < 2; ++mi)
            #pragma unroll
            for (int r = 0; r < 4; ++r) {
                int i = wm * 32 + mi * 16 + fg * 4 + r;
                int gy = y0 + (i >> 3), gx = x0 + (i & 7);
                if (gy < y_lim) {
                    size_t base = (((size_t)b * onr + (gy - oy0)) * W + gx) * COT + co0;
                    ushort h, l;
                    f32_split(fmaxf(acc[mi][0][r], 0.f), h, l);
                    out[base + wn * 32 + fr] = h;
                    out[base + wn * 32 + fr + opl] = l;
                    f32_split(fmaxf(acc[mi][1][r], 0.f), h, l);
                    out[base + wn * 32 + 16 + fr] = h;
                    out[base + wn * 32 + 16 + fr + opl] = l;
                }
            }
    }
}

// ---------------------------------------------------------------------------
// Detector head: 1x1 conv (256->65) + softmax(65) + drop dustbin + pixel
// shuffle to [8,480,640]. cpa = f16 hi/lo planes [38400][256]. Wave per pixel.
// ---------------------------------------------------------------------------
__global__ __launch_bounds__(256) void scores_kernel(
    const ushort* __restrict__ cpa, size_t cpl, const float* __restrict__ wpb,
    const float* __restrict__ bpb, float* __restrict__ sc)
{
    __shared__ __align__(16) float wT[128][66];
    __shared__ __align__(16) float xs[4][256];
    int t = threadIdx.x;
    int wave = t >> 6, lane = t & 63;
    int p = blockIdx.x * 4 + wave;

    ushort4 xh = *reinterpret_cast<const ushort4*>(&cpa[(size_t)p * 256 + lane * 4]);
    ushort4 xl = *reinterpret_cast<const ushort4*>(&cpa[(size_t)p * 256 + lane * 4 + cpl]);
    xs[wave][lane * 4 + 0] = h2f(xh.x) + h2f(xl.x);
    xs[wave][lane * 4 + 1] = h2f(xh.y) + h2f(xl.y);
    xs[wave][lane * 4 + 2] = h2f(xh.z) + h2f(xl.z);
    xs[wave][lane * 4 + 3] = h2f(xh.w) + h2f(xl.w);

    float a = bpb[lane];
    float a2 = bpb[64];
    for (int k0 = 0; k0 < 256; k0 += 128) {
        __syncthreads();
        for (int idx = t; idx < 65 * 128; idx += 256) {
            int o = idx / 128, i = idx % 128;
            wT[i][o] = wpb[o * 256 + k0 + i];
        }
        __syncthreads();
        for (int i = 0; i < 128; ++i) {
            float xb = xs[wave][k0 + i];
            a  = fmaf(xb, wT[i][lane], a);
            a2 = fmaf(xb, wT[i][64], a2);
        }
    }
    float m = a;
    #pragma unroll
    for (int off = 32; off; off >>= 1) m = fmaxf(m, __shfl_xor(m, off));
    m = fmaxf(m, a2);
    float e = expf(a - m);
    float s = e;
    #pragma unroll
    for (int off = 32; off; off >>= 1) s += __shfl_xor(s, off);
    s += expf(a2 - m);
    float r = e / s;
    int b = p / 4800, hw = p % 4800, h = hw / 80, w = hw % 80;
    int rr = lane >> 3, cc = lane & 7;
    sc[b * 307200 + (h * 8 + rr) * 640 + (w * 8 + cc)] = r;
}

// ---------------------------------------------------------------------------
// NMS: 16x16 tile + radius-3 halo, 7x7 max with -inf padding. (fp32)
// ---------------------------------------------------------------------------
#define NMS_STAGE(SRC)                                                        \
    __shared__ float ts[22][23];                                              \
    const int H = 480, W = 640;                                               \
    int bx = blockIdx.x * 16, by = blockIdx.y * 16, b = blockIdx.z;           \
    int t = threadIdx.x;                                                      \
    for (int idx = t; idx < 22 * 22; idx += 256) {                            \
        int yy = idx / 22, xx = idx % 22;                                     \
        int gy = by + yy - 3, gx = bx + xx - 3;                               \
        ts[yy][xx] = (gy >= 0 && gy < H && gx >= 0 && gx < W)                 \
                         ? (SRC)[b * 307200 + gy * W + gx] : -INFINITY;       \
    }                                                                         \
    __syncthreads();                                                          \
    int lx = t & 15, ly = t >> 4;                                             \
    float mx = -INFINITY;                                                     \
    _Pragma("unroll")                                                         \
    for (int dy = 0; dy < 7; ++dy)                                            \
        _Pragma("unroll")                                                     \
        for (int dx = 0; dx < 7; ++dx)                                       \
            mx = fmaxf(mx, ts[ly + dy][lx + dx]);                            \
    int p = b * 307200 + (by + ly) * W + (bx + lx);

__global__ __launch_bounds__(256) void nms_max_mask(
    const float* __restrict__ s, float* __restrict__ M)
{
    NMS_STAGE(s)
    M[p] = (ts[ly + 3][lx + 3] == mx) ? 1.f : 0.f;
}

__global__ __launch_bounds__(256) void nms_supp(
    const float* __restrict__ M, const float* __restrict__ s,
    float* __restrict__ supp, float* __restrict__ ss)
{
    NMS_STAGE(M)
    float sup = (mx > 0.f) ? 1.f : 0.f;
    supp[p] = sup;
    ss[p] = (sup > 0.f) ? 0.f : s[p];
}

template<bool LAST>
__global__ __launch_bounds__(256) void nms_update(
    const float* __restrict__ ssb, const float* __restrict__ supp,
    const float* __restrict__ s, float* __restrict__ M, float* __restrict__ outp)
{
    NMS_STAGE(ssb)
    bool new_max = (ts[ly + 3][lx + 3] == mx);
    float mo = M[p];
    float sp = supp[p];
    bool mn = (mo > 0.f) || (new_max && sp == 0.f);
    if (LAST)
        outp[p] = mn ? s[p] : 0.f;
    else
        M[p] = mn ? 1.f : 0.f;
}

// ---------------------------------------------------------------------------
// Descriptor head: 1x1 conv (256->256) + bias + per-pixel L2 normalize.
// f16 hi/lo NHWC input [38400][256] -> NCHW fp32 output [8][256][4800].
// ---------------------------------------------------------------------------
__global__ __launch_bounds__(256, 2) void descdb_kernel(
    const ushort* __restrict__ cda, size_t cpl, const float* __restrict__ wdb,
    const float* __restrict__ bdb, float* __restrict__ outp)
{
    __shared__ __align__(16) float Xs[16][65];
    __shared__ __align__(16) float Ws[16][257];
    int t = threadIdx.x;
    int m0 = blockIdx.x * 64;
    int n_id = t & 31, m_id = t >> 5;

    float acc[8][8];
    #pragma unroll
    for (int nn = 0; nn < 8; ++nn) {
        float bv = bdb[n_id + 32 * nn];
        #pragma unroll
        for (int mm = 0; mm < 8; ++mm) acc[mm][nn] = bv;
    }

    for (int k0 = 0; k0 < 256; k0 += 16) {
        __syncthreads();
        for (int idx = t; idx < 64 * 16; idx += 256) {
            int m = idx / 16, k = idx % 16;
            size_t a = (size_t)(m0 + m) * 256 + k0 + k;
            Xs[k][m] = h2f(cda[a]) + h2f(cda[a + cpl]);
        }
        for (int idx = t; idx < 256 * 16; idx += 256) {
            int o = idx / 16, k = idx % 16;
            Ws[k][o] = wdb[o * 256 + k0 + k];
        }
        __syncthreads();
        #pragma unroll
        for (int k = 0; k < 16; ++k) {
            float xv[8], wv[8];
            #pragma unroll
            for (int mm = 0; mm < 8; ++mm) xv[mm] = Xs[k][m_id * 8 + mm];
            #pragma unroll
            for (int nn = 0; nn < 8; ++nn) wv[nn] = Ws[k][n_id + 32 * nn];
            #pragma unroll
            for (int mm = 0; mm < 8; ++mm)
                #pragma unroll
                for (int nn = 0; nn < 8; ++nn)
                    acc[mm][nn] = fmaf(xv[mm], wv[nn], acc[mm][nn]);
        }
    }
    #pragma unroll
    for (int mm = 0; mm < 8; ++mm) {
        float sq = 0.f;
        #pragma unroll
        for (int nn = 0; nn < 8; ++nn) sq = fmaf(acc[mm][nn], acc[mm][nn], sq);
        #pragma unroll
        for (int off = 16; off; off >>= 1) sq += __shfl_xor(sq, off);
        float inv = 1.f / sqrtf(sq);
        int P = m0 + m_id * 8 + mm;
        int b = P / 4800, hw = P % 4800;
        #pragma unroll
        for (int nn = 0; nn < 8; ++nn) {
            int o = n_id + 32 * nn;
            outp[(b * 256 + o) * 4800 + hw] = acc[mm][nn] * inv;
        }
    }
}

// ---------------------------------------------------------------------------
extern "C" void kernel_launch(void* const* d_in, const int* in_sizes, int n_in,
                              void* d_out, int out_size, void* d_ws, size_t ws_size,
                              hipStream_t stream)
{
    const float* image = (const float*)d_in[0];
    const float* w1a = (const float*)d_in[1];  const float* b1a = (const float*)d_in[2];
    const float* w1b = (const float*)d_in[3];  const float* b1b = (const float*)d_in[4];
    const float* w2a = (const float*)d_in[5];  const float* b2a = (const float*)d_in[6];
    const float* w2b = (const float*)d_in[7];  const float* b2b = (const float*)d_in[8];
    const float* w3a = (const float*)d_in[9];  const float* b3a = (const float*)d_in[10];
    const float* w3b = (const float*)d_in[11]; const float* b3b = (const float*)d_in[12];
    const float* w4a = (const float*)d_in[13]; const float* b4a = (const float*)d_in[14];
    const float* w4b = (const float*)d_in[15]; const float* b4b = (const float*)d_in[16];
    const float* wPa = (const float*)d_in[17]; const float* bPa = (const float*)d_in[18];
    const float* wPb = (const float*)d_in[19]; const float* bPb = (const float*)d_in[20];
    const float* wDa = (const float*)d_in[21]; const float* bDa = (const float*)d_in[22];
    const float* wDb = (const float*)d_in[23]; const float* bDb = (const float*)d_in[24];

    float* out_sc   = (float*)d_out;            // [8,480,640]
    float* out_nms  = out_sc + 2457600;         // [8,480,640]
    float* out_desc = out_sc + 4915200;         // [8,256,60,80]

    ushort* U = (ushort*)d_ws;
    // weights
    const int O1B = 0, O2A = 36864, O2B = 73728, O3A = 110592, O3B = 184320,
              O4A = 331776, O4B = 479232, OPA = 626688, ODA = 921600;
    const size_t TOT = 1216512;
    ushort* Whi = U;
    ushort* Wlo = U + TOT;
    // activation buffers (ushort offsets; peak 63.7M ushorts = 127.3 MB)
    ushort* A1b = U + 2500000;    // band <=64 rows: 2 x 10,485,760
    ushort* A2b = U + 23500000;   // band <=62 rows: 2 x 10,158,080
    ushort* A3  = U + 44000000;   // [8,120,160,64]  2 x 9,830,400
    ushort* A4  = U + 2500000;    // [8,120,160,128] 2 x 19,660,800
    ushort* A5  = U + 44000000;   // [8,60,80,128]   2 x 4,915,200
    ushort* A6  = U + 2500000;    // [8,60,80,128]
    ushort* A7  = U + 13000000;   // [8,60,80,128]
    ushort* cPa = U + 23500000;   // [8,60,80,256]   2 x 9,830,400
    ushort* cDa = U + 23500000;
    float* nmsMb  = (float*)(U + 44000000);      // 3 x 2,457,600 floats
    float* nmsSup = nmsMb + 2457600;
    float* nmsSs  = nmsSup + 2457600;

    // weight transforms (fp32 OIHW -> f16 hi/lo [9][CO][CI])
    struct WE { const float* w; int off, co, ci; };
    WE WL[9] = {{w1b, O1B, 64, 64},  {w2a, O2A, 64, 64},  {w2b, O2B, 64, 64},
                {w3a, O3A, 128, 64}, {w3b, O3B, 128, 128},{w4a, O4A, 128, 128},
                {w4b, O4B, 128, 128},{wPa, OPA, 256, 128},{wDa, ODA, 256, 128}};
    for (int i = 0; i < 9; ++i) {
        int n = WL[i].co * WL[i].ci * 9;
        wtr_kernel<<<(n + 255) / 256, 256, 0, stream>>>(
            WL[i].w, Whi + WL[i].off, Wlo + WL[i].off, WL[i].co, WL[i].ci);
    }

    const size_t P3 = 9830400, P4 = 19660800, P5 = 4915200, PP = 9830400;

    // --- stage 1+2 striped: conv1(fused)+pool -> conv2a -> conv2b+pool ---
    for (int r0 = 0; r0 < 240; r0 += 60) {
        int r1 = r0 + 60;
        int a0 = r0 - 2 < 0 ? 0 : r0 - 2, a1 = r1 + 2 > 240 ? 240 : r1 + 2;
        int anr = a1 - a0;
        size_t P1 = (size_t)8 * anr * 320 * 64;
        int ty1 = (2 * anr + 7) / 8;
        mconv_kernel<64, true, true><<<dim3(80 * ty1, 1, 8), 256, 0, stream>>>(
            nullptr, 0, image, w1a, b1a, Whi + O1B, Wlo + O1B, b1b,
            A1b, P1, 480, 640, 64, 80, 0, 480, 2 * a0, a1, a0, anr);

        int c0 = r0 - 1 < 0 ? 0 : r0 - 1, c1 = r1 + 1 > 240 ? 240 : r1 + 1;
        int cnr = c1 - c0;
        size_t P2 = (size_t)8 * cnr * 320 * 64;
        int ty2 = (cnr + 7) / 8;
        mconv_kernel<64, false, false><<<dim3(40 * ty2, 1, 8), 256, 0, stream>>>(
            A1b, P1, nullptr, nullptr, nullptr, Whi + O2A, Wlo + O2A, b2a,
            A2b, P2, 240, 320, 64, 40, a0, anr, c0, c1, c0, cnr);

        mconv_kernel<64, true, false><<<dim3(40 * 8, 1, 8), 256, 0, stream>>>(
            A2b, P2, nullptr, nullptr, nullptr, Whi + O2B, Wlo + O2B, b2b,
            A3, P3, 240, 320, 64, 40, c0, cnr, r0, r1 / 2, 0, 120);
    }

    // --- stage 3 (full) ---
    mconv_kernel<64, false, false><<<dim3(20 * 15, 2, 8), 256, 0, stream>>>(
        A3, P3, nullptr, nullptr, nullptr, Whi + O3A, Wlo + O3A, b3a,
        A4, P4, 120, 160, 128, 20, 0, 120, 0, 120, 0, 120);
    mconv_kernel<128, true, false><<<dim3(20 * 15, 2, 8), 256, 0, stream>>>(
        A4, P4, nullptr, nullptr, nullptr, Whi + O3B, Wlo + O3B, b3b,
        A5, P5, 120, 160, 128, 20, 0, 120, 0, 60, 0, 60);

    // --- stage 4 ---
    mconv_kernel<128, false, false><<<dim3(10 * 8, 2, 8), 256, 0, stream>>>(
        A5, P5, nullptr, nullptr, nullptr, Whi + O4A, Wlo + O4A, b4a,
        A6, P5, 60, 80, 128, 10, 0, 60, 0, 60, 0, 60);
    mconv_kernel<128, false, false><<<dim3(10 * 8, 2, 8), 256, 0, stream>>>(
        A6, P5, nullptr, nullptr, nullptr, Whi + O4B, Wlo + O4B, b4b,
        A7, P5, 60, 80, 128, 10, 0, 60, 0, 60, 0, 60);

    // --- detector head ---
    mconv_kernel<128, false, false><<<dim3(10 * 8, 4, 8), 256, 0, stream>>>(
        A7, P5, nullptr, nullptr, nullptr, Whi + OPA, Wlo + OPA, bPa,
        cPa, PP, 60, 80, 256, 10, 0, 60, 0, 60, 0, 60);
    scores_kernel<<<9600, 256, 0, stream>>>(cPa, PP, wPb, bPb, out_sc);

    // --- NMS (radius 3, 2 rounds) ---
    nms_max_mask<<<dim3(40, 30, 8), 256, 0, stream>>>(out_sc, nmsMb);
    nms_supp<<<dim3(40, 30, 8), 256, 0, stream>>>(nmsMb, out_sc, nmsSup, nmsSs);
    nms_update<false><<<dim3(40, 30, 8), 256, 0, stream>>>(nmsSs, nmsSup, out_sc, nmsMb, out_nms);
    nms_supp<<<dim3(40, 30, 8), 256, 0, stream>>>(nmsMb, out_sc, nmsSup, nmsSs);
    nms_update<true><<<dim3(40, 30, 8), 256, 0, stream>>>(nmsSs, nmsSup, out_sc, nmsMb, out_nms);

    // --- descriptor head ---
    mconv_kernel<128, false, false><<<dim3(10 * 8, 4, 8), 256, 0, stream>>>(
        A7, P5, nullptr, nullptr, nullptr, Whi + ODA, Wlo + ODA, bDa,
        cDa, PP, 60, 80, 256, 10, 0, 60, 0, 60, 0, 60);
    descdb_kernel<<<600, 256, 0, stream>>>(cDa, PP, wDb, bDb, out_desc);
}

// Round 6
// 2827.662 us; speedup vs baseline: 3.8756x; 2.6955x over previous
//
#include <hip/hip_runtime.h>
#include <math.h>

typedef __attribute__((ext_vector_type(8))) _Float16 f16x8;
typedef __attribute__((ext_vector_type(4))) float f32x4;

__device__ __forceinline__ void f32_split(float x, ushort& h, ushort& l) {
    _Float16 hh = (_Float16)x;
    float r = x - (float)hh;
    _Float16 ll = (_Float16)r;
    union { _Float16 f; ushort u; } a, b;
    a.f = hh; b.f = ll;
    h = a.u; l = b.u;
}
__device__ __forceinline__ float h2f(ushort u) {
    union { ushort u; _Float16 f; } v; v.u = u; return (float)v.f;
}

// ---------------------------------------------------------------------------
// Weight transform: fp32 OIHW [CO][CI][3][3] -> f16 hi/lo tap-major [9][CO][CI]
// ---------------------------------------------------------------------------
__global__ void wtr_kernel(const float* __restrict__ src, ushort* __restrict__ dhi,
                           ushort* __restrict__ dlo, int CO, int CI)
{
    int n = CO * CI * 9, coci = CO * CI;
    for (int idx = blockIdx.x * 256 + threadIdx.x; idx < n; idx += gridDim.x * 256) {
        int tp = idx / coci, r = idx % coci;
        int co = r / CI, ci = r % CI;
        ushort h, l;
        f32_split(src[((size_t)co * CI + ci) * 9 + tp], h, l);
        dhi[idx] = h; dlo[idx] = l;
    }
}

// ---------------------------------------------------------------------------
// Split-f16 MFMA implicit-GEMM conv3x3 + relu (+pool), v2 schedule.
// Block: 128 px (16 rows x 8 cols) x (32*NR) out-ch; 4 waves 2M x 2N.
// Wave: 64 px x (16*NR) co. A (activations) staged in LDS per CI-64 chunk;
// W (weights) read per-lane from global (L2-resident) -> NO barriers in K-loop.
// Each product = 3 MFMAs: ah*wh + al*wh + ah*wl (fp32 accumulate).
// ---------------------------------------------------------------------------
template<int CI, int NR, bool POOL, bool FUSE1A>
__global__ __launch_bounds__(256, NR == 2 ? 3 : 2) void mconv2_kernel(
    const ushort* __restrict__ in, size_t ipl,
    const float* __restrict__ image, const float* __restrict__ w1a,
    const float* __restrict__ b1a,
    const ushort* __restrict__ whi, const ushort* __restrict__ wlo, // [9][COT][CI]
    const float* __restrict__ bias,
    ushort* __restrict__ out, size_t opl,
    int H, int W, int COT, int TXC,
    int iy0, int inr, int y_start, int y_lim, int oy0, int onr)
{
    // A halo: 18 rows x 10 cols = 180 px, CIP=72 pad, hi+lo planes.
    __shared__ __align__(16) ushort asmem[2][12960];
    __shared__ float fshared[FUSE1A ? 880 : 4];
    ushort* AHI = asmem[0];
    ushort* ALO = asmem[1];

    int t = threadIdx.x;
    int tx = blockIdx.x % TXC, ty = blockIdx.x / TXC;
    int x0 = tx * 8, y0 = y_start + ty * 16;
    int co0 = blockIdx.y * (32 * NR);
    int b = blockIdx.z;

    int lane = t & 63, wid = t >> 6;
    int wm = wid >> 1, wn = wid & 1;
    int fr = lane & 15, fg = lane >> 4;

    // A-frag LDS base per mi: px = wm*64 + mi*16 + fr
    int habase[4];
    #pragma unroll
    for (int mi = 0; mi < 4; ++mi) {
        int p = wm * 64 + mi * 16 + fr;
        habase[mi] = ((p >> 3) * 10 + (p & 7)) * 72 + fg * 8;
    }
    // W-frag global row offsets per nj
    size_t wro[NR];
    #pragma unroll
    for (int nj = 0; nj < NR; ++nj) {
        int cog = co0 + wn * NR * 16 + nj * 16 + fr;
        wro[nj] = (size_t)cog * CI + fg * 8;
    }

    f32x4 acc[4][NR];
    #pragma unroll
    for (int nj = 0; nj < NR; ++nj) {
        float bv = bias[co0 + wn * NR * 16 + nj * 16 + fr];
        #pragma unroll
        for (int mi = 0; mi < 4; ++mi)
            acc[mi][nj] = f32x4{bv, bv, bv, bv};
    }

    const int NC = CI / 64;
    for (int cc = 0; cc < NC; ++cc) {
        if (cc > 0) __syncthreads();
        // ---- stage A chunk (180 halo px x 64 ch, hi+lo) ----
        if constexpr (FUSE1A) {
            float* img_s = fshared;          // 20x12 = 240
            float* w1a_s = fshared + 240;    // 576
            float* b1a_s = fshared + 816;    // 64
            for (int idx = t; idx < 240; idx += 256) {
                int iy = idx / 12, ix = idx % 12;
                int gy = y0 - 2 + iy, gx = x0 - 2 + ix;
                img_s[idx] = (gy >= 0 && gy < H && gx >= 0 && gx < W)
                                 ? image[((size_t)b * H + gy) * W + gx] : 0.f;
            }
            for (int idx = t; idx < 576; idx += 256) w1a_s[idx] = w1a[idx];
            if (t < 64) b1a_s[t] = b1a[t];
            __syncthreads();
            for (int idx = t; idx < 11520; idx += 256) {   // 180 px x 64 ch
                int hp = idx >> 6, c = idx & 63;
                int hpy = hp / 10, hpx = hp % 10;
                int gy = y0 - 1 + hpy, gx = x0 - 1 + hpx;
                float v = 0.f;
                if (gy >= 0 && gy < H && gx >= 0 && gx < W) {
                    float s = b1a_s[c];
                    #pragma unroll
                    for (int ky = 0; ky < 3; ++ky)
                        #pragma unroll
                        for (int kx = 0; kx < 3; ++kx)
                            s = fmaf(img_s[(hpy + ky) * 12 + hpx + kx],
                                     w1a_s[c * 9 + ky * 3 + kx], s);
                    v = fmaxf(s, 0.f);
                }
                ushort h, l; f32_split(v, h, l);
                AHI[hp * 72 + c] = h;
                ALO[hp * 72 + c] = l;
            }
        } else {
            for (int idx = t; idx < 1440; idx += 256) {   // 180 px x 8 int4-units
                int hp = idx >> 3, c8 = idx & 7;
                int hy = y0 - 1 + hp / 10, hx = x0 - 1 + hp % 10;
                int4 vh = make_int4(0, 0, 0, 0), vl = make_int4(0, 0, 0, 0);
                if (hy >= iy0 && hy < iy0 + inr && hx >= 0 && hx < W) {
                    size_t a = (((size_t)b * inr + (hy - iy0)) * W + hx) * CI + cc * 64 + c8 * 8;
                    vh = *reinterpret_cast<const int4*>(&in[a]);
                    vl = *reinterpret_cast<const int4*>(&in[a + ipl]);
                }
                *reinterpret_cast<int4*>(&AHI[hp * 72 + c8 * 8]) = vh;
                *reinterpret_cast<int4*>(&ALO[hp * 72 + c8 * 8]) = vl;
            }
        }
        __syncthreads();

        // ---- K-loop: 9 taps x 2 k-chunks, no barriers ----
        #pragma unroll 1
        for (int tap = 0; tap < 9; ++tap) {
            const ushort* wtH = whi + (size_t)tap * COT * CI + cc * 64;
            const ushort* wtL = wlo + (size_t)tap * COT * CI + cc * 64;
            f16x8 wh[2][NR], wl[2][NR];
            #pragma unroll
            for (int kc = 0; kc < 2; ++kc)
                #pragma unroll
                for (int nj = 0; nj < NR; ++nj) {
                    wh[kc][nj] = *reinterpret_cast<const f16x8*>(&wtH[wro[nj] + kc * 32]);
                    wl[kc][nj] = *reinterpret_cast<const f16x8*>(&wtL[wro[nj] + kc * 32]);
                }
            int ky = tap / 3, kx = tap - ky * 3;
            int hoff = (ky * 10 + kx) * 72;
            #pragma unroll
            for (int kc = 0; kc < 2; ++kc) {
                f16x8 ah[4], al[4];
                #pragma unroll
                for (int mi = 0; mi < 4; ++mi) {
                    ah[mi] = *reinterpret_cast<const f16x8*>(&AHI[habase[mi] + hoff + kc * 32]);
                    al[mi] = *reinterpret_cast<const f16x8*>(&ALO[habase[mi] + hoff + kc * 32]);
                }
                #pragma unroll
                for (int mi = 0; mi < 4; ++mi)
                    #pragma unroll
                    for (int nj = 0; nj < NR; ++nj) {
                        acc[mi][nj] = __builtin_amdgcn_mfma_f32_16x16x32_f16(ah[mi], wh[kc][nj], acc[mi][nj], 0, 0, 0);
                        acc[mi][nj] = __builtin_amdgcn_mfma_f32_16x16x32_f16(al[mi], wh[kc][nj], acc[mi][nj], 0, 0, 0);
                        acc[mi][nj] = __builtin_amdgcn_mfma_f32_16x16x32_f16(ah[mi], wl[kc][nj], acc[mi][nj], 0, 0, 0);
                    }
            }
        }
    }

    // ---- epilogue ----
    if constexpr (POOL) {
        // px = wm*64 + mi*16 + fg*4 + r : y = wm*8+mi*2+(fg>>1), x = (fg&1)*4+r
        // pool pairs: x^1 = r^1 (in-lane), y^1 = fg^2 (lane^32)
        int Wp = W >> 1;
        #pragma unroll
        for (int mi = 0; mi < 4; ++mi) {
            int qy = (y0 >> 1) + wm * 4 + mi;
            #pragma unroll
            for (int nj = 0; nj < NR; ++nj) {
                f32x4 v = acc[mi][nj];
                float v0 = fmaxf(v[0], 0.f), v1 = fmaxf(v[1], 0.f);
                float v2 = fmaxf(v[2], 0.f), v3 = fmaxf(v[3], 0.f);
                float mA = fmaxf(v0, v1), mB = fmaxf(v2, v3);
                float pA = fmaxf(mA, __shfl_xor(mA, 32));
                float pB = fmaxf(mB, __shfl_xor(mB, 32));
                if ((fg & 2) == 0 && qy < y_lim) {
                    int qx = (x0 >> 1) + (fg & 1) * 2;
                    int cog = co0 + wn * NR * 16 + nj * 16 + fr;
                    size_t oa = (((size_t)b * onr + (qy - oy0)) * Wp + qx) * COT + cog;
                    ushort h, l;
                    f32_split(pA, h, l);
                    out[oa] = h; out[oa + opl] = l;
                    f32_split(pB, h, l);
                    out[oa + COT] = h; out[oa + COT + opl] = l;
                }
            }
        }
    } else {
        #pragma unroll
        for (int mi = 0; mi < 4; ++mi)
            #pragma unroll
            for (int r = 0; r < 4; ++r) {
                int gy = y0 + wm * 8 + mi * 2 + (fg >> 1);
                int gx = x0 + (fg & 1) * 4 + r;
                if (gy < y_lim) {
                    size_t base = (((size_t)b * onr + (gy - oy0)) * W + gx) * COT;
                    #pragma unroll
                    for (int nj = 0; nj < NR; ++nj) {
                        int cog = co0 + wn * NR * 16 + nj * 16 + fr;
                        ushort h, l;
                        f32_split(fmaxf(acc[mi][nj][r], 0.f), h, l);
                        out[base + cog] = h;
                        out[base + cog + opl] = l;
                    }
                }
            }
    }
}

// ---------------------------------------------------------------------------
// Detector head: 1x1 conv (256->65) + softmax(65) + drop dustbin + pixel
// shuffle to [8,480,640]. cpa = f16 hi/lo planes [38400][256]. Wave per pixel.
// ---------------------------------------------------------------------------
__global__ __launch_bounds__(256) void scores_kernel(
    const ushort* __restrict__ cpa, size_t cpl, const float* __restrict__ wpb,
    const float* __restrict__ bpb, float* __restrict__ sc)
{
    __shared__ __align__(16) float wT[128][66];
    __shared__ __align__(16) float xs[4][256];
    int t = threadIdx.x;
    int wave = t >> 6, lane = t & 63;
    int p = blockIdx.x * 4 + wave;

    ushort4 xh = *reinterpret_cast<const ushort4*>(&cpa[(size_t)p * 256 + lane * 4]);
    ushort4 xl = *reinterpret_cast<const ushort4*>(&cpa[(size_t)p * 256 + lane * 4 + cpl]);
    xs[wave][lane * 4 + 0] = h2f(xh.x) + h2f(xl.x);
    xs[wave][lane * 4 + 1] = h2f(xh.y) + h2f(xl.y);
    xs[wave][lane * 4 + 2] = h2f(xh.z) + h2f(xl.z);
    xs[wave][lane * 4 + 3] = h2f(xh.w) + h2f(xl.w);

    float a = bpb[lane];
    float a2 = bpb[64];
    for (int k0 = 0; k0 < 256; k0 += 128) {
        __syncthreads();
        for (int idx = t; idx < 65 * 128; idx += 256) {
            int o = idx / 128, i = idx % 128;
            wT[i][o] = wpb[o * 256 + k0 + i];
        }
        __syncthreads();
        for (int i = 0; i < 128; ++i) {
            float xb = xs[wave][k0 + i];
            a  = fmaf(xb, wT[i][lane], a);
            a2 = fmaf(xb, wT[i][64], a2);
        }
    }
    float m = a;
    #pragma unroll
    for (int off = 32; off; off >>= 1) m = fmaxf(m, __shfl_xor(m, off));
    m = fmaxf(m, a2);
    float e = expf(a - m);
    float s = e;
    #pragma unroll
    for (int off = 32; off; off >>= 1) s += __shfl_xor(s, off);
    s += expf(a2 - m);
    float r = e / s;
    int b = p / 4800, hw = p % 4800, h = hw / 80, w = hw % 80;
    int rr = lane >> 3, cc = lane & 7;
    sc[b * 307200 + (h * 8 + rr) * 640 + (w * 8 + cc)] = r;
}

// ---------------------------------------------------------------------------
// NMS: 16x16 tile + radius-3 halo, 7x7 max with -inf padding. (fp32)
// ---------------------------------------------------------------------------
#define NMS_STAGE(SRC)                                                        \
    __shared__ float ts[22][23];                                              \
    const int H = 480, W = 640;                                               \
    int bx = blockIdx.x * 16, by = blockIdx.y * 16, b = blockIdx.z;           \
    int t = threadIdx.x;                                                      \
    for (int idx = t; idx < 22 * 22; idx += 256) {                            \
        int yy = idx / 22, xx = idx % 22;                                     \
        int gy = by + yy - 3, gx = bx + xx - 3;                               \
        ts[yy][xx] = (gy >= 0 && gy < H && gx >= 0 && gx < W)                 \
                         ? (SRC)[b * 307200 + gy * W + gx] : -INFINITY;       \
    }                                                                         \
    __syncthreads();                                                          \
    int lx = t & 15, ly = t >> 4;                                             \
    float mx = -INFINITY;                                                     \
    _Pragma("unroll")                                                         \
    for (int dy = 0; dy < 7; ++dy)                                            \
        _Pragma("unroll")                                                     \
        for (int dx = 0; dx < 7; ++dx)                                       \
            mx = fmaxf(mx, ts[ly + dy][lx + dx]);                            \
    int p = b * 307200 + (by + ly) * W + (bx + lx);

__global__ __launch_bounds__(256) void nms_max_mask(
    const float* __restrict__ s, float* __restrict__ M)
{
    NMS_STAGE(s)
    M[p] = (ts[ly + 3][lx + 3] == mx) ? 1.f : 0.f;
}

__global__ __launch_bounds__(256) void nms_supp(
    const float* __restrict__ M, const float* __restrict__ s,
    float* __restrict__ supp, float* __restrict__ ss)
{
    NMS_STAGE(M)
    float sup = (mx > 0.f) ? 1.f : 0.f;
    supp[p] = sup;
    ss[p] = (sup > 0.f) ? 0.f : s[p];
}

template<bool LAST>
__global__ __launch_bounds__(256) void nms_update(
    const float* __restrict__ ssb, const float* __restrict__ supp,
    const float* __restrict__ s, float* __restrict__ M, float* __restrict__ outp)
{
    NMS_STAGE(ssb)
    bool new_max = (ts[ly + 3][lx + 3] == mx);
    float mo = M[p];
    float sp = supp[p];
    bool mn = (mo > 0.f) || (new_max && sp == 0.f);
    if (LAST)
        outp[p] = mn ? s[p] : 0.f;
    else
        M[p] = mn ? 1.f : 0.f;
}

// ---------------------------------------------------------------------------
// Descriptor head: 1x1 conv (256->256) + bias + per-pixel L2 normalize.
// f16 hi/lo NHWC input [38400][256] -> NCHW fp32 output [8][256][4800].
// ---------------------------------------------------------------------------
__global__ __launch_bounds__(256, 2) void descdb_kernel(
    const ushort* __restrict__ cda, size_t cpl, const float* __restrict__ wdb,
    const float* __restrict__ bdb, float* __restrict__ outp)
{
    __shared__ __align__(16) float Xs[16][65];
    __shared__ __align__(16) float Ws[16][257];
    int t = threadIdx.x;
    int m0 = blockIdx.x * 64;
    int n_id = t & 31, m_id = t >> 5;

    float acc[8][8];
    #pragma unroll
    for (int nn = 0; nn < 8; ++nn) {
        float bv = bdb[n_id + 32 * nn];
        #pragma unroll
        for (int mm = 0; mm < 8; ++mm) acc[mm][nn] = bv;
    }

    for (int k0 = 0; k0 < 256; k0 += 16) {
        __syncthreads();
        for (int idx = t; idx < 64 * 16; idx += 256) {
            int m = idx / 16, k = idx % 16;
            size_t a = (size_t)(m0 + m) * 256 + k0 + k;
            Xs[k][m] = h2f(cda[a]) + h2f(cda[a + cpl]);
        }
        for (int idx = t; idx < 256 * 16; idx += 256) {
            int o = idx / 16, k = idx % 16;
            Ws[k][o] = wdb[o * 256 + k0 + k];
        }
        __syncthreads();
        #pragma unroll
        for (int k = 0; k < 16; ++k) {
            float xv[8], wv[8];
            #pragma unroll
            for (int mm = 0; mm < 8; ++mm) xv[mm] = Xs[k][m_id * 8 + mm];
            #pragma unroll
            for (int nn = 0; nn < 8; ++nn) wv[nn] = Ws[k][n_id + 32 * nn];
            #pragma unroll
            for (int mm = 0; mm < 8; ++mm)
                #pragma unroll
                for (int nn = 0; nn < 8; ++nn)
                    acc[mm][nn] = fmaf(xv[mm], wv[nn], acc[mm][nn]);
        }
    }
    #pragma unroll
    for (int mm = 0; mm < 8; ++mm) {
        float sq = 0.f;
        #pragma unroll
        for (int nn = 0; nn < 8; ++nn) sq = fmaf(acc[mm][nn], acc[mm][nn], sq);
        #pragma unroll
        for (int off = 16; off; off >>= 1) sq += __shfl_xor(sq, off);
        float inv = 1.f / sqrtf(sq);
        int P = m0 + m_id * 8 + mm;
        int b = P / 4800, hw = P % 4800;
        #pragma unroll
        for (int nn = 0; nn < 8; ++nn) {
            int o = n_id + 32 * nn;
            outp[(b * 256 + o) * 4800 + hw] = acc[mm][nn] * inv;
        }
    }
}

// ---------------------------------------------------------------------------
extern "C" void kernel_launch(void* const* d_in, const int* in_sizes, int n_in,
                              void* d_out, int out_size, void* d_ws, size_t ws_size,
                              hipStream_t stream)
{
    const float* image = (const float*)d_in[0];
    const float* w1a = (const float*)d_in[1];  const float* b1a = (const float*)d_in[2];
    const float* w1b = (const float*)d_in[3];  const float* b1b = (const float*)d_in[4];
    const float* w2a = (const float*)d_in[5];  const float* b2a = (const float*)d_in[6];
    const float* w2b = (const float*)d_in[7];  const float* b2b = (const float*)d_in[8];
    const float* w3a = (const float*)d_in[9];  const float* b3a = (const float*)d_in[10];
    const float* w3b = (const float*)d_in[11]; const float* b3b = (const float*)d_in[12];
    const float* w4a = (const float*)d_in[13]; const float* b4a = (const float*)d_in[14];
    const float* w4b = (const float*)d_in[15]; const float* b4b = (const float*)d_in[16];
    const float* wPa = (const float*)d_in[17]; const float* bPa = (const float*)d_in[18];
    const float* wPb = (const float*)d_in[19]; const float* bPb = (const float*)d_in[20];
    const float* wDa = (const float*)d_in[21]; const float* bDa = (const float*)d_in[22];
    const float* wDb = (const float*)d_in[23]; const float* bDb = (const float*)d_in[24];

    float* out_sc   = (float*)d_out;            // [8,480,640]
    float* out_nms  = out_sc + 2457600;         // [8,480,640]
    float* out_desc = out_sc + 4915200;         // [8,256,60,80]

    ushort* U = (ushort*)d_ws;
    const int O1B = 0, O2A = 36864, O2B = 73728, O3A = 110592, O3B = 184320,
              O4A = 331776, O4B = 479232, OPA = 626688, ODA = 921600;
    const size_t TOT = 1216512;
    ushort* Whi = U;
    ushort* Wlo = U + TOT;
    ushort* A1b = U + 2500000;    // conv1 band (<=64 pooled rows): 2 x 10,485,760
    ushort* A2b = U + 23500000;   // conv2a band (<=62 rows): 2 x 10,158,080
    ushort* A3  = U + 44000000;   // [8,120,160,64]  2 x 9,830,400
    ushort* A4  = U + 2500000;    // [8,120,160,128] 2 x 19,660,800
    ushort* A5  = U + 44000000;   // [8,60,80,128]   2 x 4,915,200
    ushort* A6  = U + 2500000;    // [8,60,80,128]
    ushort* A7  = U + 13000000;   // [8,60,80,128]
    ushort* cPa = U + 23500000;   // [8,60,80,256]   2 x 9,830,400
    ushort* cDa = U + 23500000;
    float* nmsMb  = (float*)(U + 44000000);
    float* nmsSup = nmsMb + 2457600;
    float* nmsSs  = nmsSup + 2457600;

    struct WE { const float* w; int off, co, ci; };
    WE WL[9] = {{w1b, O1B, 64, 64},  {w2a, O2A, 64, 64},  {w2b, O2B, 64, 64},
                {w3a, O3A, 128, 64}, {w3b, O3B, 128, 128},{w4a, O4A, 128, 128},
                {w4b, O4B, 128, 128},{wPa, OPA, 256, 128},{wDa, ODA, 256, 128}};
    for (int i = 0; i < 9; ++i) {
        int n = WL[i].co * WL[i].ci * 9;
        wtr_kernel<<<(n + 255) / 256, 256, 0, stream>>>(
            WL[i].w, Whi + WL[i].off, Wlo + WL[i].off, WL[i].co, WL[i].ci);
    }

    const size_t P3 = 9830400, P4 = 19660800, P5 = 4915200, PP = 9830400;

    // --- stage 1+2 striped: conv1(fused)+pool -> conv2a -> conv2b+pool ---
    for (int r0 = 0; r0 < 240; r0 += 60) {
        int r1 = r0 + 60;
        int a0 = r0 - 2 < 0 ? 0 : r0 - 2, a1 = r1 + 2 > 240 ? 240 : r1 + 2;
        int anr = a1 - a0;
        size_t P1 = (size_t)8 * anr * 320 * 64;
        int ty1 = (2 * anr + 15) / 16;
        mconv2_kernel<64, 2, true, true><<<dim3(80 * ty1, 1, 8), 256, 0, stream>>>(
            nullptr, 0, image, w1a, b1a, Whi + O1B, Wlo + O1B, b1b,
            A1b, P1, 480, 640, 64, 80, 0, 480, 2 * a0, a1, a0, anr);

        int c0 = r0 - 1 < 0 ? 0 : r0 - 1, c1 = r1 + 1 > 240 ? 240 : r1 + 1;
        int cnr = c1 - c0;
        size_t P2 = (size_t)8 * cnr * 320 * 64;
        int ty2 = (cnr + 15) / 16;
        mconv2_kernel<64, 2, false, false><<<dim3(40 * ty2, 1, 8), 256, 0, stream>>>(
            A1b, P1, nullptr, nullptr, nullptr, Whi + O2A, Wlo + O2A, b2a,
            A2b, P2, 240, 320, 64, 40, a0, anr, c0, c1, c0, cnr);

        mconv2_kernel<64, 2, true, false><<<dim3(40 * 8, 1, 8), 256, 0, stream>>>(
            A2b, P2, nullptr, nullptr, nullptr, Whi + O2B, Wlo + O2B, b2b,
            A3, P3, 240, 320, 64, 40, c0, cnr, 2 * r0, r1, 0, 120);
    }

    // --- stage 3 (full) ---
    mconv2_kernel<64, 4, false, false><<<dim3(20 * 8, 1, 8), 256, 0, stream>>>(
        A3, P3, nullptr, nullptr, nullptr, Whi + O3A, Wlo + O3A, b3a,
        A4, P4, 120, 160, 128, 20, 0, 120, 0, 120, 0, 120);
    mconv2_kernel<128, 4, true, false><<<dim3(20 * 8, 1, 8), 256, 0, stream>>>(
        A4, P4, nullptr, nullptr, nullptr, Whi + O3B, Wlo + O3B, b3b,
        A5, P5, 120, 160, 128, 20, 0, 120, 0, 60, 0, 60);

    // --- stage 4 ---
    mconv2_kernel<128, 4, false, false><<<dim3(10 * 4, 1, 8), 256, 0, stream>>>(
        A5, P5, nullptr, nullptr, nullptr, Whi + O4A, Wlo + O4A, b4a,
        A6, P5, 60, 80, 128, 10, 0, 60, 0, 60, 0, 60);
    mconv2_kernel<128, 4, false, false><<<dim3(10 * 4, 1, 8), 256, 0, stream>>>(
        A6, P5, nullptr, nullptr, nullptr, Whi + O4B, Wlo + O4B, b4b,
        A7, P5, 60, 80, 128, 10, 0, 60, 0, 60, 0, 60);

    // --- detector head ---
    mconv2_kernel<128, 4, false, false><<<dim3(10 * 4, 2, 8), 256, 0, stream>>>(
        A7, P5, nullptr, nullptr, nullptr, Whi + OPA, Wlo + OPA, bPa,
        cPa, PP, 60, 80, 256, 10, 0, 60, 0, 60, 0, 60);
    scores_kernel<<<9600, 256, 0, stream>>>(cPa, PP, wPb, bPb, out_sc);

    // --- NMS (radius 3, 2 rounds) ---
    nms_max_mask<<<dim3(40, 30, 8), 256, 0, stream>>>(out_sc, nmsMb);
    nms_supp<<<dim3(40, 30, 8), 256, 0, stream>>>(nmsMb, out_sc, nmsSup, nmsSs);
    nms_update<false><<<dim3(40, 30, 8), 256, 0, stream>>>(nmsSs, nmsSup, out_sc, nmsMb, out_nms);
    nms_supp<<<dim3(40, 30, 8), 256, 0, stream>>>(nmsMb, out_sc, nmsSup, nmsSs);
    nms_update<true><<<dim3(40, 30, 8), 256, 0, stream>>>(nmsSs, nmsSup, out_sc, nmsMb, out_nms);

    // --- descriptor head ---
    mconv2_kernel<128, 4, false, false><<<dim3(10 * 4, 2, 8), 256, 0, stream>>>(
        A7, P5, nullptr, nullptr, nullptr, Whi + ODA, Wlo + ODA, bDa,
        cDa, PP, 60, 80, 256, 10, 0, 60, 0, 60, 0, 60);
    descdb_kernel<<<600, 256, 0, stream>>>(cDa, PP, wDb, bDb, out_desc);
}